// Round 10
// baseline (148.708 us; speedup 1.0000x reference)
//
#include <hip/hip_runtime.h>
#include <hip/hip_bf16.h>

#define NN 512
#define DD 128

typedef __bf16 bf16x8 __attribute__((ext_vector_type(8)));
typedef float f32x4 __attribute__((ext_vector_type(4)));

static __device__ __forceinline__ f32x4 mfma16(bf16x8 a, bf16x8 b, f32x4 c) {
  return __builtin_amdgcn_mfma_f32_16x16x32_bf16(a, b, c, 0, 0, 0);
}

// -------- phase 0 (fused): w1t transpose + hjp + cnt --------
__global__ void k_pre(const float* __restrict__ h,
                      const float* __restrict__ msg_w1,
                      const float* __restrict__ msg_b1,
                      const int* __restrict__ emask,
                      __bf16* __restrict__ w1t, float* __restrict__ hjp,
                      float* __restrict__ cnt) {
  __shared__ float hr[128];
  __shared__ int csum;
  int j = blockIdx.x, t = threadIdx.x;
  if (t == 0) csum = 0;
  hr[t] = h[j * 128 + t];
  __syncthreads();
  float acc = msg_b1[t];
  #pragma unroll 8
  for (int k = 0; k < 128; k++) acc += hr[k] * msg_w1[k * 128 + t];
  hjp[j * 128 + t] = acc;
  // w1t[e][k] = msg_w1[128+k][e] : 32 elements per block
  if (t < 32) {
    int tt = j * 32 + t;
    int e = tt >> 7, k = tt & 127;
    w1t[e * 128 + k] = (__bf16)msg_w1[(128 + k) * 128 + e];
  }
  // cnt[j] = sum_r emask[r][j]
  int s = 0;
  #pragma unroll
  for (int r = 0; r < 4; r++) s += emask[(t * 4 + r) * NN + j] ? 1 : 0;
  #pragma unroll
  for (int off = 32; off > 0; off >>= 1) s += __shfl_down(s, off, 64);
  if ((t & 63) == 0) atomicAdd(&csum, s);
  __syncthreads();
  if (t == 0) cnt[j] = (float)csum;
}

// ---------------- phase 1: T[i][e] = sum_j mask[j,i]*silu(pre[j,i,e]) ----
// GEMM2 hoisted out of the N^2 loop. Mask-skip (predicated loads) halves
// the rel stream; 1-deep pipeline carries bfr (16 regs, not x's 32):
//   top: issue j+1 predicated loads -> compute j from bfr -> bottom: cvt.
// __launch_bounds__(256,3): unified cap ~170. Live set ~120 fits ->
// 3 waves/SIMD, 3 blocks/CU (12 waves/CU). Cap 128 provokes the 64/64
// arch/acc split + spills (R1-R7); cap 256 gave only 8 waves/CU (R9).
#define LDS_BYTES 34816

#define LOADX(rp) \
  x0 = *(const f32x4*)(rp);        x1 = *(const f32x4*)((rp) + 4);  \
  x2 = *(const f32x4*)((rp) + 32); x3 = *(const f32x4*)((rp) + 36); \
  x4 = *(const f32x4*)((rp) + 64); x5 = *(const f32x4*)((rp) + 68); \
  x6 = *(const f32x4*)((rp) + 96); x7 = *(const f32x4*)((rp) + 100);

#define CVTALL() { \
  CVT(bfr0, x0, x1) CVT(bfr1, x2, x3) CVT(bfr2, x4, x5) CVT(bfr3, x6, x7) }

#define CVT(bf, xa, xb) { \
  bf[0] = (__bf16)xa[0]; bf[1] = (__bf16)xa[1]; \
  bf[2] = (__bf16)xa[2]; bf[3] = (__bf16)xa[3]; \
  bf[4] = (__bf16)xb[0]; bf[5] = (__bf16)xb[1]; \
  bf[6] = (__bf16)xb[2]; bf[7] = (__bf16)xb[3]; }

__global__ __launch_bounds__(256, 3) void k_main(
    const float* __restrict__ rel, const int* __restrict__ emask,
    const float* __restrict__ hjp, const __bf16* __restrict__ w1t_g,
    float* __restrict__ partial) {
  extern __shared__ char smem[];
  __bf16* w1t = (__bf16*)smem;
  const int tid = threadIdx.x;
  const int wave = tid >> 6;
  const int lane = tid & 63;
  const int l15 = lane & 15;
  const int q = lane >> 4;

  // stage w1t into padded LDS (row stride 272B): 256 thr x 8 bf16 x 8
  {
    int t = tid * 8;
    #pragma unroll
    for (int t0 = 0; t0 < 8; t0++) {
      int tt = t + t0 * 2048;
      int e = tt >> 7, k8 = tt & 127;
      *(bf16x8*)(w1t + e * 136 + k8) = *(const bf16x8*)(w1t_g + e * 128 + k8);
    }
  }
  __syncthreads();

  const int it = blockIdx.x >> 5;    // 0..31 : 16-row i-tile
  const int jc = blockIdx.x & 31;    // 0..31 : 16-col j-chunk
  const int irow = it * 16;

  // Tacc[ef][r] = T[i = l15][e = ef*16 + q*4 + r]
  f32x4 Tacc[8];
  #pragma unroll
  for (int ef = 0; ef < 8; ef++) {
    f32x4 z = {0.f, 0.f, 0.f, 0.f};
    Tacc[ef] = z;
  }

  const int jbase = jc * 16 + wave * 4;

  // prologue: zero raw regs once (stale contents thereafter are finite rel
  // data; masked contributions are multiplied by 0 -> bit-identical output)
  f32x4 x0 = {0.f, 0.f, 0.f, 0.f}, x1 = x0, x2 = x0, x3 = x0,
        x4 = x0, x5 = x0, x6 = x0, x7 = x0;
  bf16x8 bfr0, bfr1, bfr2, bfr3;
  float msCur = emask[(size_t)jbase * NN + irow + l15] ? 1.f : 0.f;
  {
    const float* rowp = rel + ((size_t)jbase * NN + irow + l15) * DD + q * 8;
    if (msCur != 0.f) { LOADX(rowp) }
  }
  CVTALL()

  #pragma unroll 1
  for (int jj = 0; jj < 4; jj++) {
    const int j = jbase + jj;
    const float ms = msCur;
    const float* hj = hjp + (size_t)j * DD;

    // issue next j's predicated loads now (land during eg-compute below)
    float msn = 0.f;
    if (jj < 3) {
      msn = emask[(size_t)(j + 1) * NN + irow + l15] ? 1.f : 0.f;
      const float* rowp = rel + ((size_t)(j + 1) * NN + irow + l15) * DD + q * 8;
      if (msn != 0.f) { LOADX(rowp) }
    }
    msCur = msn;

    // per eg: GEMM1 rows [32eg,32eg+32) -> silu -> masked accumulate
    #pragma unroll
    for (int eg = 0; eg < 4; eg++) {
      f32x4 p0 = {0.f, 0.f, 0.f, 0.f};
      f32x4 p1 = {0.f, 0.f, 0.f, 0.f};
      #define G1(KC, BFR) \
        p0 = mfma16(*(const bf16x8*)(w1t + (eg * 32 + l15) * 136 + KC * 32 + q * 8), BFR, p0); \
        p1 = mfma16(*(const bf16x8*)(w1t + (eg * 32 + 16 + l15) * 136 + KC * 32 + q * 8), BFR, p1);
      G1(0, bfr0) G1(1, bfr1) G1(2, bfr2) G1(3, bfr3)
      #undef G1
      // lane holds pre[e = 32eg + q*4 + r][i = l15] (p0), e+16 (p1)
      f32x4 hv0 = *(const f32x4*)(hj + eg * 32 + q * 4);
      f32x4 hv1 = *(const f32x4*)(hj + eg * 32 + 16 + q * 4);
      #pragma unroll
      for (int r = 0; r < 4; r++) {
        float v0 = p0[r] + hv0[r];
        float v1 = p1[r] + hv1[r];
        Tacc[2 * eg][r]     += ms * v0 * __builtin_amdgcn_rcpf(1.f + __expf(-v0));
        Tacc[2 * eg + 1][r] += ms * v1 * __builtin_amdgcn_rcpf(1.f + __expf(-v1));
      }
    }

    // convert next j's raw data (loads have had the full eg-compute to land)
    if (jj < 3) { CVTALL() }
  }

  // cross-wave reduction: reuse w1t region as 4 x [8][132] f32 bufs.
  float* fbase = (float*)smem;
  float* fb = fbase + wave * (8 * 132);
  #pragma unroll
  for (int t = 0; t < 2; t++) {
    __syncthreads();
    if ((l15 >> 3) == t) {
      #pragma unroll
      for (int ef = 0; ef < 8; ef++)
        *(f32x4*)(fb + (l15 & 7) * 132 + ef * 16 + q * 4) = Tacc[ef];
    }
    __syncthreads();
    int row8 = tid >> 5;         // 0..7
    int e4 = (tid & 31) << 2;    // 0..124 step 4
    f32x4 s = {0.f, 0.f, 0.f, 0.f};
    #pragma unroll
    for (int w = 0; w < 4; w++)
      s += *(const f32x4*)(fbase + w * (8 * 132) + row8 * 132 + e4);
    *(f32x4*)(partial + ((size_t)jc * NN + irow + t * 8 + row8) * DD + e4) = s;
  }
}

// ------- phase 2: T-reduce + GEMM2(f32) + update MLP + LayerNorm -------
__global__ void k_update(const float* __restrict__ h, const float* __restrict__ partial,
                         const float* __restrict__ w2, const float* __restrict__ b2,
                         const float* __restrict__ cnt,
                         const float* __restrict__ uw1, const float* __restrict__ ub1,
                         const float* __restrict__ uw2, const float* __restrict__ ub2,
                         const float* __restrict__ g, const float* __restrict__ bb,
                         float* __restrict__ out) {
  __shared__ float Trow[128];
  __shared__ float uin[256];
  __shared__ float zl[128];
  __shared__ float ss[4];
  int i = blockIdx.x, t = threadIdx.x;
  float hv = h[i * 128 + t];
  float ts = 0.f;
  #pragma unroll
  for (int c = 0; c < 32; c++) ts += partial[((size_t)c * NN + i) * DD + t];
  Trow[t] = ts;
  __syncthreads();
  float a = cnt[i] * b2[t];
  #pragma unroll 8
  for (int e = 0; e < 128; e++) a += Trow[e] * w2[e * 128 + t];
  uin[t] = hv;
  uin[128 + t] = a;
  __syncthreads();
  float z = ub1[t];
  #pragma unroll 8
  for (int k = 0; k < 256; k++) z += uin[k] * uw1[k * 128 + t];
  z = z / (1.f + __expf(-z));
  zl[t] = z;
  __syncthreads();
  float dl = ub2[t];
  #pragma unroll 8
  for (int k = 0; k < 128; k++) dl += zl[k] * uw2[k * 128 + t];
  float x = hv + dl;
  float s1 = x, s2 = x * x;
  #pragma unroll
  for (int off = 32; off > 0; off >>= 1) {
    s1 += __shfl_down(s1, off, 64);
    s2 += __shfl_down(s2, off, 64);
  }
  if ((t & 63) == 0) { ss[(t >> 6) * 2] = s1; ss[(t >> 6) * 2 + 1] = s2; }
  __syncthreads();
  s1 = ss[0] + ss[2];
  s2 = ss[1] + ss[3];
  float mu = s1 * (1.f / 128.f);
  float var = s2 * (1.f / 128.f) - mu * mu;
  out[i * 128 + t] = (x - mu) * rsqrtf(var + 1e-5f) * g[t] + bb[t];
}

extern "C" void kernel_launch(void* const* d_in, const int* in_sizes, int n_in,
                              void* d_out, int out_size, void* d_ws, size_t ws_size,
                              hipStream_t stream) {
  const float* h      = (const float*)d_in[0];
  const float* rel    = (const float*)d_in[1];
  const int*   emask  = (const int*)d_in[2];
  const float* msg_w1 = (const float*)d_in[3];
  const float* msg_b1 = (const float*)d_in[4];
  const float* msg_w2 = (const float*)d_in[5];
  const float* msg_b2 = (const float*)d_in[6];
  const float* upd_w1 = (const float*)d_in[7];
  const float* upd_b1 = (const float*)d_in[8];
  const float* upd_w2 = (const float*)d_in[9];
  const float* upd_b2 = (const float*)d_in[10];
  const float* ln_g   = (const float*)d_in[11];
  const float* ln_b   = (const float*)d_in[12];
  float* out = (float*)d_out;

  char* ws = (char*)d_ws;
  float*  hjp     = (float*)ws;                        // 262144 B
  __bf16* w1t     = (__bf16*)(ws + 262144);            // 32768 B
  float*  cnt     = (float*)(ws + 262144 + 32768);     // 2048 B
  float*  partial = (float*)(ws + 262144 + 36864);     // 32*512*128*4 = 8 MiB

  k_pre<<<512, 128, 0, stream>>>(h, msg_w1, msg_b1, emask, w1t, hjp, cnt);
  hipFuncSetAttribute((const void*)k_main,
                      hipFuncAttributeMaxDynamicSharedMemorySize, LDS_BYTES);
  k_main<<<1024, 256, LDS_BYTES, stream>>>(rel, emask, hjp, w1t, partial);
  k_update<<<512, 128, 0, stream>>>(h, partial, msg_w2, msg_b2, cnt,
                                    upd_w1, upd_b1, upd_w2, upd_b2,
                                    ln_g, ln_b, out);
}

// Round 11
// 59.254 us; speedup vs baseline: 2.5097x; 2.5097x over previous
//
#include <hip/hip_runtime.h>
#include <hip/hip_bf16.h>

#define NN 512
#define DD 128

typedef __bf16 bf16x8 __attribute__((ext_vector_type(8)));
typedef float f32x4 __attribute__((ext_vector_type(4)));

static __device__ __forceinline__ f32x4 mfma16(bf16x8 a, bf16x8 b, f32x4 c) {
  return __builtin_amdgcn_mfma_f32_16x16x32_bf16(a, b, c, 0, 0, 0);
}

// -------- phase 0 (fused): w1t transpose + hjp + cnt --------
__global__ void k_pre(const float* __restrict__ h,
                      const float* __restrict__ msg_w1,
                      const float* __restrict__ msg_b1,
                      const int* __restrict__ emask,
                      __bf16* __restrict__ w1t, float* __restrict__ hjp,
                      float* __restrict__ cnt) {
  __shared__ float hr[128];
  __shared__ int csum;
  int j = blockIdx.x, t = threadIdx.x;
  if (t == 0) csum = 0;
  hr[t] = h[j * 128 + t];
  __syncthreads();
  float acc = msg_b1[t];
  #pragma unroll 8
  for (int k = 0; k < 128; k++) acc += hr[k] * msg_w1[k * 128 + t];
  hjp[j * 128 + t] = acc;
  // w1t[e][k] = msg_w1[128+k][e] : 32 elements per block
  if (t < 32) {
    int tt = j * 32 + t;
    int e = tt >> 7, k = tt & 127;
    w1t[e * 128 + k] = (__bf16)msg_w1[(128 + k) * 128 + e];
  }
  // cnt[j] = sum_r emask[r][j]
  int s = 0;
  #pragma unroll
  for (int r = 0; r < 4; r++) s += emask[(t * 4 + r) * NN + j] ? 1 : 0;
  #pragma unroll
  for (int off = 32; off > 0; off >>= 1) s += __shfl_down(s, off, 64);
  if ((t & 63) == 0) atomicAdd(&csum, s);
  __syncthreads();
  if (t == 0) cnt[j] = (float)csum;
}

// ---------------- phase 1: T[i][e] = sum_j mask[j,i]*silu(pre[j,i,e]) ----
// Per-wave disjoint e-slice [32w,32w+32): w1 operand lives in 32 VGPRs,
// no w1t LDS, no cross-wave reduction (direct partial writes). rel rows
// staged cooperatively via double-buffered LDS tile [16][132] f32 (padded
// stride -> uniform bank spread); per-thread staging cost = 32B (8 VGPR).
// Mask-skip on stage load+write (stale rows = older finite data; jj<2
// writes unconditionally so uninitialized LDS is never read -> no 0*NaN).
// Live set ~105 VGPR; (256,2) = cap 256, the only proven-spill-free cap
// (R1-R10: any cap<256 -> arch/acc split -> 88-270MB scratch traffic).
#define CVT(bf, xa, xb) { \
  bf[0] = (__bf16)xa[0]; bf[1] = (__bf16)xa[1]; \
  bf[2] = (__bf16)xa[2]; bf[3] = (__bf16)xa[3]; \
  bf[4] = (__bf16)xb[0]; bf[5] = (__bf16)xb[1]; \
  bf[6] = (__bf16)xb[2]; bf[7] = (__bf16)xb[3]; }

__global__ __launch_bounds__(256, 2) void k_main(
    const float* __restrict__ rel, const int* __restrict__ emask,
    const float* __restrict__ hjp, const __bf16* __restrict__ w1t_g,
    float* __restrict__ partial) {
  __shared__ __align__(16) float tile[2 * 16 * 132];
  const int tid = threadIdx.x;
  const int wave = tid >> 6;
  const int lane = tid & 63;
  const int l15 = lane & 15;
  const int q = lane >> 4;

  const int it = blockIdx.x >> 5;    // 0..31 : 16-row i-tile
  const int jc = blockIdx.x & 31;    // 0..31 : 16-col j-chunk
  const int irow = it * 16;
  const int jbase = jc * 16;

  // wave-private w1 fragments for e-slice [32w, 32w+32):
  // awHk = w1t[32w + H*16 + l15][k*32 + q*8 .. +8]
  bf16x8 aw00, aw01, aw02, aw03, aw10, aw11, aw12, aw13;
  {
    const __bf16* b0 = w1t_g + (wave * 32 + l15) * 128 + q * 8;
    aw00 = *(const bf16x8*)(b0);
    aw01 = *(const bf16x8*)(b0 + 32);
    aw02 = *(const bf16x8*)(b0 + 64);
    aw03 = *(const bf16x8*)(b0 + 96);
    const __bf16* b1 = b0 + 16 * 128;
    aw10 = *(const bf16x8*)(b1);
    aw11 = *(const bf16x8*)(b1 + 32);
    aw12 = *(const bf16x8*)(b1 + 64);
    aw13 = *(const bf16x8*)(b1 + 96);
  }

  // t0[r] = T[i=l15][e=32w+q*4+r], t1 = +16
  f32x4 t0 = {0.f, 0.f, 0.f, 0.f}, t1 = t0;

  // staging role: thread covers row srow, 32B chunk schunk of the tile
  const int srow = tid >> 4;
  const int schunk = tid & 15;
  const float* sb = rel + ((size_t)jbase * NN + irow + srow) * DD + schunk * 8;
  float* sd = tile + srow * 132 + schunk * 8;
  const size_t emrow = (size_t)irow + srow;

  f32x4 xa = {0.f, 0.f, 0.f, 0.f}, xb = xa;
  float msw = emask[(size_t)jbase * NN + emrow] ? 1.f : 0.f;
  if (msw != 0.f) { xa = *(const f32x4*)sb; xb = *(const f32x4*)(sb + 4); }

  #pragma unroll 1
  for (int jj = 0; jj < 16; ++jj) {
    const int cur = jj & 1;
    // write staged row chunk for j=jbase+jj (x loaded last iter / prologue)
    float* d = sd + cur * 2112;
    if (jj < 2 || msw != 0.f) { *(f32x4*)d = xa; *(f32x4*)(d + 4) = xb; }
    // issue next j's predicated load (lands during compute below)
    if (jj < 15) {
      msw = emask[(size_t)(jbase + jj + 1) * NN + emrow] ? 1.f : 0.f;
      if (msw != 0.f) {
        const float* s = sb + (size_t)(jj + 1) * NN * DD;
        xa = *(const f32x4*)s;
        xb = *(const f32x4*)(s + 4);
      }
    }
    __syncthreads();   // tile[cur] writes visible

    const int j = jbase + jj;
    const float ms = emask[(size_t)j * NN + irow + l15] ? 1.f : 0.f;
    const float* tp = tile + cur * 2112 + l15 * 132 + q * 8;
    bf16x8 bf0, bf1, bf2, bf3;
    { f32x4 ya = *(const f32x4*)(tp);      f32x4 yb = *(const f32x4*)(tp + 4);   CVT(bf0, ya, yb) }
    { f32x4 ya = *(const f32x4*)(tp + 32); f32x4 yb = *(const f32x4*)(tp + 36);  CVT(bf1, ya, yb) }
    { f32x4 ya = *(const f32x4*)(tp + 64); f32x4 yb = *(const f32x4*)(tp + 68);  CVT(bf2, ya, yb) }
    { f32x4 ya = *(const f32x4*)(tp + 96); f32x4 yb = *(const f32x4*)(tp + 100); CVT(bf3, ya, yb) }
    f32x4 p0 = {0.f, 0.f, 0.f, 0.f}, p1 = p0;
    p0 = mfma16(aw00, bf0, p0); p1 = mfma16(aw10, bf0, p1);
    p0 = mfma16(aw01, bf1, p0); p1 = mfma16(aw11, bf1, p1);
    p0 = mfma16(aw02, bf2, p0); p1 = mfma16(aw12, bf2, p1);
    p0 = mfma16(aw03, bf3, p0); p1 = mfma16(aw13, bf3, p1);
    const float* hj = hjp + (size_t)j * DD + wave * 32 + q * 4;
    f32x4 hv0 = *(const f32x4*)(hj);
    f32x4 hv1 = *(const f32x4*)(hj + 16);
    #pragma unroll
    for (int r = 0; r < 4; r++) {
      float v0 = p0[r] + hv0[r];
      float v1 = p1[r] + hv1[r];
      t0[r] += ms * v0 * __builtin_amdgcn_rcpf(1.f + __expf(-v0));
      t1[r] += ms * v1 * __builtin_amdgcn_rcpf(1.f + __expf(-v1));
    }
    __syncthreads();   // all waves done reading tile[cur]
  }

  // direct per-wave e-slice write (no cross-wave reduction needed)
  float* pp = partial + ((size_t)jc * NN + irow + l15) * DD + wave * 32 + q * 4;
  *(f32x4*)pp = t0;
  *(f32x4*)(pp + 16) = t1;
}

// ------- phase 2: T-reduce + GEMM2(f32) + update MLP + LayerNorm -------
__global__ void k_update(const float* __restrict__ h, const float* __restrict__ partial,
                         const float* __restrict__ w2, const float* __restrict__ b2,
                         const float* __restrict__ cnt,
                         const float* __restrict__ uw1, const float* __restrict__ ub1,
                         const float* __restrict__ uw2, const float* __restrict__ ub2,
                         const float* __restrict__ g, const float* __restrict__ bb,
                         float* __restrict__ out) {
  __shared__ float Trow[128];
  __shared__ float uin[256];
  __shared__ float zl[128];
  __shared__ float ss[4];
  int i = blockIdx.x, t = threadIdx.x;
  float hv = h[i * 128 + t];
  float ts = 0.f;
  #pragma unroll
  for (int c = 0; c < 32; c++) ts += partial[((size_t)c * NN + i) * DD + t];
  Trow[t] = ts;
  __syncthreads();
  float a = cnt[i] * b2[t];
  #pragma unroll 8
  for (int e = 0; e < 128; e++) a += Trow[e] * w2[e * 128 + t];
  uin[t] = hv;
  uin[128 + t] = a;
  __syncthreads();
  float z = ub1[t];
  #pragma unroll 8
  for (int k = 0; k < 256; k++) z += uin[k] * uw1[k * 128 + t];
  z = z / (1.f + __expf(-z));
  zl[t] = z;
  __syncthreads();
  float dl = ub2[t];
  #pragma unroll 8
  for (int k = 0; k < 128; k++) dl += zl[k] * uw2[k * 128 + t];
  float x = hv + dl;
  float s1 = x, s2 = x * x;
  #pragma unroll
  for (int off = 32; off > 0; off >>= 1) {
    s1 += __shfl_down(s1, off, 64);
    s2 += __shfl_down(s2, off, 64);
  }
  if ((t & 63) == 0) { ss[(t >> 6) * 2] = s1; ss[(t >> 6) * 2 + 1] = s2; }
  __syncthreads();
  s1 = ss[0] + ss[2];
  s2 = ss[1] + ss[3];
  float mu = s1 * (1.f / 128.f);
  float var = s2 * (1.f / 128.f) - mu * mu;
  out[i * 128 + t] = (x - mu) * rsqrtf(var + 1e-5f) * g[t] + bb[t];
}

extern "C" void kernel_launch(void* const* d_in, const int* in_sizes, int n_in,
                              void* d_out, int out_size, void* d_ws, size_t ws_size,
                              hipStream_t stream) {
  const float* h      = (const float*)d_in[0];
  const float* rel    = (const float*)d_in[1];
  const int*   emask  = (const int*)d_in[2];
  const float* msg_w1 = (const float*)d_in[3];
  const float* msg_b1 = (const float*)d_in[4];
  const float* msg_w2 = (const float*)d_in[5];
  const float* msg_b2 = (const float*)d_in[6];
  const float* upd_w1 = (const float*)d_in[7];
  const float* upd_b1 = (const float*)d_in[8];
  const float* upd_w2 = (const float*)d_in[9];
  const float* upd_b2 = (const float*)d_in[10];
  const float* ln_g   = (const float*)d_in[11];
  const float* ln_b   = (const float*)d_in[12];
  float* out = (float*)d_out;

  char* ws = (char*)d_ws;
  float*  hjp     = (float*)ws;                        // 262144 B
  __bf16* w1t     = (__bf16*)(ws + 262144);            // 32768 B
  float*  cnt     = (float*)(ws + 262144 + 32768);     // 2048 B
  float*  partial = (float*)(ws + 262144 + 36864);     // 32*512*128*4 = 8 MiB

  k_pre<<<512, 128, 0, stream>>>(h, msg_w1, msg_b1, emask, w1t, hjp, cnt);
  k_main<<<1024, 256, 0, stream>>>(rel, emask, hjp, w1t, partial);
  k_update<<<512, 128, 0, stream>>>(h, partial, msg_w2, msg_b2, cnt,
                                    upd_w1, upd_b1, upd_w2, upd_b2,
                                    ln_g, ln_b, out);
}

// Round 12
// 50.609 us; speedup vs baseline: 2.9384x; 1.1708x over previous
//
#include <hip/hip_runtime.h>
#include <hip/hip_bf16.h>

#define NN 512
#define DD 128

typedef __bf16 bf16x8 __attribute__((ext_vector_type(8)));
typedef float f32x4 __attribute__((ext_vector_type(4)));

static __device__ __forceinline__ f32x4 mfma16(bf16x8 a, bf16x8 b, f32x4 c) {
  return __builtin_amdgcn_mfma_f32_16x16x32_bf16(a, b, c, 0, 0, 0);
}

// -------- phase 0 (fused): w1t transpose + hjp + cnt --------
__global__ void k_pre(const float* __restrict__ h,
                      const float* __restrict__ msg_w1,
                      const float* __restrict__ msg_b1,
                      const int* __restrict__ emask,
                      __bf16* __restrict__ w1t, float* __restrict__ hjp,
                      float* __restrict__ cnt) {
  __shared__ float hr[128];
  __shared__ int csum;
  int j = blockIdx.x, t = threadIdx.x;
  if (t == 0) csum = 0;
  hr[t] = h[j * 128 + t];
  __syncthreads();
  float acc = msg_b1[t];
  #pragma unroll 16
  for (int k = 0; k < 128; k++) acc += hr[k] * msg_w1[k * 128 + t];
  hjp[j * 128 + t] = acc;
  // w1t[e][k] = msg_w1[128+k][e] : 32 elements per block
  if (t < 32) {
    int tt = j * 32 + t;
    int e = tt >> 7, k = tt & 127;
    w1t[e * 128 + k] = (__bf16)msg_w1[(128 + k) * 128 + e];
  }
  // cnt[j] = sum_r emask[r][j]
  int s = 0;
  #pragma unroll
  for (int r = 0; r < 4; r++) s += emask[(t * 4 + r) * NN + j] ? 1 : 0;
  #pragma unroll
  for (int off = 32; off > 0; off >>= 1) s += __shfl_down(s, off, 64);
  if ((t & 63) == 0) atomicAdd(&csum, s);
  __syncthreads();
  if (t == 0) cnt[j] = (float)csum;
}

// ---------------- phase 1: T[i][e] = sum_j mask[j,i]*silu(pre[j,i,e]) ----
// Per-wave disjoint e-slice; w1 operand in 32 VGPRs; rel staged via
// double-buffered LDS tile. ONE barrier per j-step (R11 had two):
//   barrier -> publish row j+1 (ds_write from regs) -> issue load row j+2
//   -> compute row j.
// Buffer-b race check: reads of tile[b] at step jj-1 and writes of tile[b]
// at step jj are separated by barrier jj. Load j+2 has a full iteration
// (compute + barrier) before its ds_write -> HBM latency hidden (T14).
// ds_writes unconditional (stale regs finite; ms=0 masks contributions ->
// bit-identical). (256,2) = cap 256, the only spill-free cap (R1-R10).
#define CVT(bf, xa, xb) { \
  bf[0] = (__bf16)xa[0]; bf[1] = (__bf16)xa[1]; \
  bf[2] = (__bf16)xa[2]; bf[3] = (__bf16)xa[3]; \
  bf[4] = (__bf16)xb[0]; bf[5] = (__bf16)xb[1]; \
  bf[6] = (__bf16)xb[2]; bf[7] = (__bf16)xb[3]; }

__global__ __launch_bounds__(256, 2) void k_main(
    const float* __restrict__ rel, const int* __restrict__ emask,
    const float* __restrict__ hjp, const __bf16* __restrict__ w1t_g,
    float* __restrict__ partial) {
  __shared__ __align__(16) float tile[2 * 16 * 132];
  const int tid = threadIdx.x;
  const int wave = tid >> 6;
  const int lane = tid & 63;
  const int l15 = lane & 15;
  const int q = lane >> 4;

  const int it = blockIdx.x >> 5;    // 0..31 : 16-row i-tile
  const int jc = blockIdx.x & 31;    // 0..31 : 16-col j-chunk
  const int irow = it * 16;
  const int jbase = jc * 16;

  // wave-private w1 fragments for e-slice [32w, 32w+32)
  bf16x8 aw00, aw01, aw02, aw03, aw10, aw11, aw12, aw13;
  {
    const __bf16* b0 = w1t_g + (wave * 32 + l15) * 128 + q * 8;
    aw00 = *(const bf16x8*)(b0);
    aw01 = *(const bf16x8*)(b0 + 32);
    aw02 = *(const bf16x8*)(b0 + 64);
    aw03 = *(const bf16x8*)(b0 + 96);
    const __bf16* b1 = b0 + 16 * 128;
    aw10 = *(const bf16x8*)(b1);
    aw11 = *(const bf16x8*)(b1 + 32);
    aw12 = *(const bf16x8*)(b1 + 64);
    aw13 = *(const bf16x8*)(b1 + 96);
  }

  // t0[r] = T[i=l15][e=32w+q*4+r], t1 = +16
  f32x4 t0 = {0.f, 0.f, 0.f, 0.f}, t1 = t0;

  // staging role: thread covers row srow, 32B chunk schunk of the tile
  const int srow = tid >> 4;
  const int schunk = tid & 15;
  const float* sb = rel + ((size_t)jbase * NN + irow + srow) * DD + schunk * 8;
  float* sd = tile + srow * 132 + schunk * 8;
  const size_t emrow = (size_t)irow + srow;

  // prologue: zero regs once (stale contents thereafter are finite rel
  // data; ms=0 masks them exactly). Load row j0, publish to tile[0],
  // then load row j1 into regs.
  f32x4 xa = {0.f, 0.f, 0.f, 0.f}, xb = xa;
  {
    float msw = emask[(size_t)jbase * NN + emrow] ? 1.f : 0.f;
    if (msw != 0.f) { xa = *(const f32x4*)sb; xb = *(const f32x4*)(sb + 4); }
    *(f32x4*)sd = xa;
    *(f32x4*)(sd + 4) = xb;
    msw = emask[(size_t)(jbase + 1) * NN + emrow] ? 1.f : 0.f;
    if (msw != 0.f) {
      const float* s = sb + (size_t)NN * DD;
      xa = *(const f32x4*)s;
      xb = *(const f32x4*)(s + 4);
    }
  }

  #pragma unroll 1
  for (int jj = 0; jj < 16; ++jj) {
    __syncthreads();   // publishes tile[jj&1]; separates prev reads of tile[(jj+1)&1]

    // publish row jj+1 (loaded last iteration) to the other buffer
    if (jj < 15) {
      float* d = sd + (((jj + 1) & 1) ? 2112 : 0);
      *(f32x4*)d = xa;
      *(f32x4*)(d + 4) = xb;
    }
    // issue load of row jj+2 (has the full compute phase + barrier to land)
    if (jj < 14) {
      float msw = emask[(size_t)(jbase + jj + 2) * NN + emrow] ? 1.f : 0.f;
      if (msw != 0.f) {
        const float* s = sb + (size_t)(jj + 2) * NN * DD;
        xa = *(const f32x4*)s;
        xb = *(const f32x4*)(s + 4);
      }
    }

    // compute row jj from tile[jj&1]
    const int j = jbase + jj;
    const float ms = emask[(size_t)j * NN + irow + l15] ? 1.f : 0.f;
    const float* tp = tile + ((jj & 1) ? 2112 : 0) + l15 * 132 + q * 8;
    bf16x8 bf0, bf1, bf2, bf3;
    { f32x4 ya = *(const f32x4*)(tp);      f32x4 yb = *(const f32x4*)(tp + 4);   CVT(bf0, ya, yb) }
    { f32x4 ya = *(const f32x4*)(tp + 32); f32x4 yb = *(const f32x4*)(tp + 36);  CVT(bf1, ya, yb) }
    { f32x4 ya = *(const f32x4*)(tp + 64); f32x4 yb = *(const f32x4*)(tp + 68);  CVT(bf2, ya, yb) }
    { f32x4 ya = *(const f32x4*)(tp + 96); f32x4 yb = *(const f32x4*)(tp + 100); CVT(bf3, ya, yb) }
    f32x4 p0 = {0.f, 0.f, 0.f, 0.f}, p1 = p0;
    p0 = mfma16(aw00, bf0, p0); p1 = mfma16(aw10, bf0, p1);
    p0 = mfma16(aw01, bf1, p0); p1 = mfma16(aw11, bf1, p1);
    p0 = mfma16(aw02, bf2, p0); p1 = mfma16(aw12, bf2, p1);
    p0 = mfma16(aw03, bf3, p0); p1 = mfma16(aw13, bf3, p1);
    const float* hj = hjp + (size_t)j * DD + wave * 32 + q * 4;
    f32x4 hv0 = *(const f32x4*)(hj);
    f32x4 hv1 = *(const f32x4*)(hj + 16);
    #pragma unroll
    for (int r = 0; r < 4; r++) {
      float v0 = p0[r] + hv0[r];
      float v1 = p1[r] + hv1[r];
      t0[r] += ms * v0 * __builtin_amdgcn_rcpf(1.f + __expf(-v0));
      t1[r] += ms * v1 * __builtin_amdgcn_rcpf(1.f + __expf(-v1));
    }
  }

  // direct per-wave e-slice write (no cross-wave reduction needed)
  float* pp = partial + ((size_t)jc * NN + irow + l15) * DD + wave * 32 + q * 4;
  *(f32x4*)pp = t0;
  *(f32x4*)(pp + 16) = t1;
}

// ------- phase 2: T-reduce + GEMM2(f32) + update MLP + LayerNorm -------
__global__ void k_update(const float* __restrict__ h, const float* __restrict__ partial,
                         const float* __restrict__ w2, const float* __restrict__ b2,
                         const float* __restrict__ cnt,
                         const float* __restrict__ uw1, const float* __restrict__ ub1,
                         const float* __restrict__ uw2, const float* __restrict__ ub2,
                         const float* __restrict__ g, const float* __restrict__ bb,
                         float* __restrict__ out) {
  __shared__ float Trow[128];
  __shared__ float uin[256];
  __shared__ float zl[128];
  __shared__ float ss[4];
  int i = blockIdx.x, t = threadIdx.x;
  float hv = h[i * 128 + t];
  float ts = 0.f;
  #pragma unroll
  for (int c = 0; c < 32; c++) ts += partial[((size_t)c * NN + i) * DD + t];
  Trow[t] = ts;
  __syncthreads();
  float a = cnt[i] * b2[t];
  #pragma unroll 16
  for (int e = 0; e < 128; e++) a += Trow[e] * w2[e * 128 + t];
  uin[t] = hv;
  uin[128 + t] = a;
  __syncthreads();
  float z = ub1[t];
  #pragma unroll 16
  for (int k = 0; k < 256; k++) z += uin[k] * uw1[k * 128 + t];
  z = z / (1.f + __expf(-z));
  zl[t] = z;
  __syncthreads();
  float dl = ub2[t];
  #pragma unroll 16
  for (int k = 0; k < 128; k++) dl += zl[k] * uw2[k * 128 + t];
  float x = hv + dl;
  float s1 = x, s2 = x * x;
  #pragma unroll
  for (int off = 32; off > 0; off >>= 1) {
    s1 += __shfl_down(s1, off, 64);
    s2 += __shfl_down(s2, off, 64);
  }
  if ((t & 63) == 0) { ss[(t >> 6) * 2] = s1; ss[(t >> 6) * 2 + 1] = s2; }
  __syncthreads();
  s1 = ss[0] + ss[2];
  s2 = ss[1] + ss[3];
  float mu = s1 * (1.f / 128.f);
  float var = s2 * (1.f / 128.f) - mu * mu;
  out[i * 128 + t] = (x - mu) * rsqrtf(var + 1e-5f) * g[t] + bb[t];
}

extern "C" void kernel_launch(void* const* d_in, const int* in_sizes, int n_in,
                              void* d_out, int out_size, void* d_ws, size_t ws_size,
                              hipStream_t stream) {
  const float* h      = (const float*)d_in[0];
  const float* rel    = (const float*)d_in[1];
  const int*   emask  = (const int*)d_in[2];
  const float* msg_w1 = (const float*)d_in[3];
  const float* msg_b1 = (const float*)d_in[4];
  const float* msg_w2 = (const float*)d_in[5];
  const float* msg_b2 = (const float*)d_in[6];
  const float* upd_w1 = (const float*)d_in[7];
  const float* upd_b1 = (const float*)d_in[8];
  const float* upd_w2 = (const float*)d_in[9];
  const float* upd_b2 = (const float*)d_in[10];
  const float* ln_g   = (const float*)d_in[11];
  const float* ln_b   = (const float*)d_in[12];
  float* out = (float*)d_out;

  char* ws = (char*)d_ws;
  float*  hjp     = (float*)ws;                        // 262144 B
  __bf16* w1t     = (__bf16*)(ws + 262144);            // 32768 B
  float*  cnt     = (float*)(ws + 262144 + 32768);     // 2048 B
  float*  partial = (float*)(ws + 262144 + 36864);     // 32*512*128*4 = 8 MiB

  k_pre<<<512, 128, 0, stream>>>(h, msg_w1, msg_b1, emask, w1t, hjp, cnt);
  k_main<<<1024, 256, 0, stream>>>(rel, emask, hjp, w1t, partial);
  k_update<<<512, 128, 0, stream>>>(h, partial, msg_w2, msg_b2, cnt,
                                    upd_w1, upd_b1, upd_w2, upd_b2,
                                    ln_g, ln_b, out);
}

// Round 13
// 49.844 us; speedup vs baseline: 2.9835x; 1.0153x over previous
//
#include <hip/hip_runtime.h>
#include <hip/hip_bf16.h>

#define NN 512
#define DD 128

typedef __bf16 bf16x8 __attribute__((ext_vector_type(8)));
typedef float f32x4 __attribute__((ext_vector_type(4)));

static __device__ __forceinline__ f32x4 mfma16(bf16x8 a, bf16x8 b, f32x4 c) {
  return __builtin_amdgcn_mfma_f32_16x16x32_bf16(a, b, c, 0, 0, 0);
}

// -------- phase 0 (fused): w1t transpose + hjp + cnt --------
__global__ void k_pre(const float* __restrict__ h,
                      const float* __restrict__ msg_w1,
                      const float* __restrict__ msg_b1,
                      const int* __restrict__ emask,
                      __bf16* __restrict__ w1t, float* __restrict__ hjp,
                      float* __restrict__ cnt) {
  __shared__ float hr[128];
  __shared__ int csum;
  int j = blockIdx.x, t = threadIdx.x;
  if (t == 0) csum = 0;
  hr[t] = h[j * 128 + t];
  __syncthreads();
  float acc = msg_b1[t];
  #pragma unroll 16
  for (int k = 0; k < 128; k++) acc += hr[k] * msg_w1[k * 128 + t];
  hjp[j * 128 + t] = acc;
  // w1t[e][k] = msg_w1[128+k][e] : 32 elements per block
  if (t < 32) {
    int tt = j * 32 + t;
    int e = tt >> 7, k = tt & 127;
    w1t[e * 128 + k] = (__bf16)msg_w1[(128 + k) * 128 + e];
  }
  // cnt[j] = sum_r emask[r][j]
  int s = 0;
  #pragma unroll
  for (int r = 0; r < 4; r++) s += emask[(t * 4 + r) * NN + j] ? 1 : 0;
  #pragma unroll
  for (int off = 32; off > 0; off >>= 1) s += __shfl_down(s, off, 64);
  if ((t & 63) == 0) atomicAdd(&csum, s);
  __syncthreads();
  if (t == 0) cnt[j] = (float)csum;
}

// ---------------- phase 1: T[i][e] = sum_j mask[j,i]*silu(pre[j,i,e]) ----
// Per-wave disjoint e-slice; w1 operand in 32 VGPRs. rel staged through a
// double-buffered LDS tile **in bf16** (stage thread converts its 8 floats
// once, writes 16B): halves LDS bytes vs f32 staging and removes all
// compute-side cvts -- compute lanes ds_read their MFMA fragments directly.
// Numerically identical (same f32->bf16 rounding, done pre-LDS).
// One barrier per j-step: barrier -> publish j+1 -> issue load j+2 ->
// compute j (loads get a full iteration to land, T14). ds_writes
// unconditional; stale regs finite; ms=0 masks exactly.
// Bank balance (272B stride): read dword addr = 68*l15+16*kc+4*q ->
// group (l15+q)%8, uniform -> minimum-cycle wave access; same for writes.
// (256,2) = cap 256, the only spill-free cap (R1-R10 allocator law).
#define CVT(bf, xa, xb) { \
  bf[0] = (__bf16)xa[0]; bf[1] = (__bf16)xa[1]; \
  bf[2] = (__bf16)xa[2]; bf[3] = (__bf16)xa[3]; \
  bf[4] = (__bf16)xb[0]; bf[5] = (__bf16)xb[1]; \
  bf[6] = (__bf16)xb[2]; bf[7] = (__bf16)xb[3]; }

__global__ __launch_bounds__(256, 2) void k_main(
    const float* __restrict__ rel, const int* __restrict__ emask,
    const float* __restrict__ hjp, const __bf16* __restrict__ w1t_g,
    float* __restrict__ partial) {
  __shared__ __align__(16) __bf16 tile[2 * 16 * 136];
  const int tid = threadIdx.x;
  const int wave = tid >> 6;
  const int lane = tid & 63;
  const int l15 = lane & 15;
  const int q = lane >> 4;

  const int it = blockIdx.x >> 5;    // 0..31 : 16-row i-tile
  const int jc = blockIdx.x & 31;    // 0..31 : 16-col j-chunk
  const int irow = it * 16;
  const int jbase = jc * 16;

  // wave-private w1 fragments for e-slice [32w, 32w+32)
  bf16x8 aw00, aw01, aw02, aw03, aw10, aw11, aw12, aw13;
  {
    const __bf16* b0 = w1t_g + (wave * 32 + l15) * 128 + q * 8;
    aw00 = *(const bf16x8*)(b0);
    aw01 = *(const bf16x8*)(b0 + 32);
    aw02 = *(const bf16x8*)(b0 + 64);
    aw03 = *(const bf16x8*)(b0 + 96);
    const __bf16* b1 = b0 + 16 * 128;
    aw10 = *(const bf16x8*)(b1);
    aw11 = *(const bf16x8*)(b1 + 32);
    aw12 = *(const bf16x8*)(b1 + 64);
    aw13 = *(const bf16x8*)(b1 + 96);
  }

  // t0[r] = T[i=l15][e=32w+q*4+r], t1 = +16
  f32x4 t0 = {0.f, 0.f, 0.f, 0.f}, t1 = t0;

  // staging role: thread covers row srow, 8-float chunk schunk of the tile
  const int srow = tid >> 4;
  const int schunk = tid & 15;
  const float* sb = rel + ((size_t)jbase * NN + irow + srow) * DD + schunk * 8;
  __bf16* sd = tile + srow * 136 + schunk * 8;
  const size_t emrow = (size_t)irow + srow;

  // prologue: zero regs once (stale contents thereafter are finite rel
  // data; ms=0 masks them exactly). Publish row j0 as bf16, load row j1.
  f32x4 xa = {0.f, 0.f, 0.f, 0.f}, xb = xa;
  {
    float msw = emask[(size_t)jbase * NN + emrow] ? 1.f : 0.f;
    if (msw != 0.f) { xa = *(const f32x4*)sb; xb = *(const f32x4*)(sb + 4); }
    bf16x8 pub;
    CVT(pub, xa, xb)
    *(bf16x8*)sd = pub;
    msw = emask[(size_t)(jbase + 1) * NN + emrow] ? 1.f : 0.f;
    if (msw != 0.f) {
      const float* s = sb + (size_t)NN * DD;
      xa = *(const f32x4*)s;
      xb = *(const f32x4*)(s + 4);
    }
  }

  #pragma unroll 1
  for (int jj = 0; jj < 16; ++jj) {
    __syncthreads();   // publishes tile[jj&1]; separates prev reads of tile[(jj+1)&1]

    // publish row jj+1 (loaded last iteration) to the other buffer, as bf16
    if (jj < 15) {
      bf16x8 pub;
      CVT(pub, xa, xb)
      *(bf16x8*)(sd + (((jj + 1) & 1) ? 2176 : 0)) = pub;
    }
    // issue load of row jj+2 (has the full compute phase + barrier to land)
    if (jj < 14) {
      float msw = emask[(size_t)(jbase + jj + 2) * NN + emrow] ? 1.f : 0.f;
      if (msw != 0.f) {
        const float* s = sb + (size_t)(jj + 2) * NN * DD;
        xa = *(const f32x4*)s;
        xb = *(const f32x4*)(s + 4);
      }
    }

    // compute row jj from tile[jj&1]: fragments read directly as bf16
    const int j = jbase + jj;
    const float ms = emask[(size_t)j * NN + irow + l15] ? 1.f : 0.f;
    const __bf16* tp = tile + ((jj & 1) ? 2176 : 0) + l15 * 136 + q * 8;
    bf16x8 bf0 = *(const bf16x8*)(tp);
    bf16x8 bf1 = *(const bf16x8*)(tp + 32);
    bf16x8 bf2 = *(const bf16x8*)(tp + 64);
    bf16x8 bf3 = *(const bf16x8*)(tp + 96);
    f32x4 p0 = {0.f, 0.f, 0.f, 0.f}, p1 = p0;
    p0 = mfma16(aw00, bf0, p0); p1 = mfma16(aw10, bf0, p1);
    p0 = mfma16(aw01, bf1, p0); p1 = mfma16(aw11, bf1, p1);
    p0 = mfma16(aw02, bf2, p0); p1 = mfma16(aw12, bf2, p1);
    p0 = mfma16(aw03, bf3, p0); p1 = mfma16(aw13, bf3, p1);
    const float* hj = hjp + (size_t)j * DD + wave * 32 + q * 4;
    f32x4 hv0 = *(const f32x4*)(hj);
    f32x4 hv1 = *(const f32x4*)(hj + 16);
    #pragma unroll
    for (int r = 0; r < 4; r++) {
      float v0 = p0[r] + hv0[r];
      float v1 = p1[r] + hv1[r];
      t0[r] += ms * v0 * __builtin_amdgcn_rcpf(1.f + __expf(-v0));
      t1[r] += ms * v1 * __builtin_amdgcn_rcpf(1.f + __expf(-v1));
    }
  }

  // direct per-wave e-slice write (no cross-wave reduction needed)
  float* pp = partial + ((size_t)jc * NN + irow + l15) * DD + wave * 32 + q * 4;
  *(f32x4*)pp = t0;
  *(f32x4*)(pp + 16) = t1;
}

// ------- phase 2: T-reduce + GEMM2(f32) + update MLP + LayerNorm -------
__global__ void k_update(const float* __restrict__ h, const float* __restrict__ partial,
                         const float* __restrict__ w2, const float* __restrict__ b2,
                         const float* __restrict__ cnt,
                         const float* __restrict__ uw1, const float* __restrict__ ub1,
                         const float* __restrict__ uw2, const float* __restrict__ ub2,
                         const float* __restrict__ g, const float* __restrict__ bb,
                         float* __restrict__ out) {
  __shared__ float Trow[128];
  __shared__ float uin[256];
  __shared__ float zl[128];
  __shared__ float ss[4];
  int i = blockIdx.x, t = threadIdx.x;
  float hv = h[i * 128 + t];
  float ts = 0.f;
  #pragma unroll
  for (int c = 0; c < 32; c++) ts += partial[((size_t)c * NN + i) * DD + t];
  Trow[t] = ts;
  __syncthreads();
  float a = cnt[i] * b2[t];
  #pragma unroll 16
  for (int e = 0; e < 128; e++) a += Trow[e] * w2[e * 128 + t];
  uin[t] = hv;
  uin[128 + t] = a;
  __syncthreads();
  float z = ub1[t];
  #pragma unroll 16
  for (int k = 0; k < 256; k++) z += uin[k] * uw1[k * 128 + t];
  z = z / (1.f + __expf(-z));
  zl[t] = z;
  __syncthreads();
  float dl = ub2[t];
  #pragma unroll 16
  for (int k = 0; k < 128; k++) dl += zl[k] * uw2[k * 128 + t];
  float x = hv + dl;
  float s1 = x, s2 = x * x;
  #pragma unroll
  for (int off = 32; off > 0; off >>= 1) {
    s1 += __shfl_down(s1, off, 64);
    s2 += __shfl_down(s2, off, 64);
  }
  if ((t & 63) == 0) { ss[(t >> 6) * 2] = s1; ss[(t >> 6) * 2 + 1] = s2; }
  __syncthreads();
  s1 = ss[0] + ss[2];
  s2 = ss[1] + ss[3];
  float mu = s1 * (1.f / 128.f);
  float var = s2 * (1.f / 128.f) - mu * mu;
  out[i * 128 + t] = (x - mu) * rsqrtf(var + 1e-5f) * g[t] + bb[t];
}

extern "C" void kernel_launch(void* const* d_in, const int* in_sizes, int n_in,
                              void* d_out, int out_size, void* d_ws, size_t ws_size,
                              hipStream_t stream) {
  const float* h      = (const float*)d_in[0];
  const float* rel    = (const float*)d_in[1];
  const int*   emask  = (const int*)d_in[2];
  const float* msg_w1 = (const float*)d_in[3];
  const float* msg_b1 = (const float*)d_in[4];
  const float* msg_w2 = (const float*)d_in[5];
  const float* msg_b2 = (const float*)d_in[6];
  const float* upd_w1 = (const float*)d_in[7];
  const float* upd_b1 = (const float*)d_in[8];
  const float* upd_w2 = (const float*)d_in[9];
  const float* upd_b2 = (const float*)d_in[10];
  const float* ln_g   = (const float*)d_in[11];
  const float* ln_b   = (const float*)d_in[12];
  float* out = (float*)d_out;

  char* ws = (char*)d_ws;
  float*  hjp     = (float*)ws;                        // 262144 B
  __bf16* w1t     = (__bf16*)(ws + 262144);            // 32768 B
  float*  cnt     = (float*)(ws + 262144 + 32768);     // 2048 B
  float*  partial = (float*)(ws + 262144 + 36864);     // 32*512*128*4 = 8 MiB

  k_pre<<<512, 128, 0, stream>>>(h, msg_w1, msg_b1, emask, w1t, hjp, cnt);
  k_main<<<1024, 256, 0, stream>>>(rel, emask, hjp, w1t, partial);
  k_update<<<512, 128, 0, stream>>>(h, partial, msg_w2, msg_b2, cnt,
                                    upd_w1, upd_b1, upd_w2, upd_b2,
                                    ln_g, ln_b, out);
}

// Round 14
// 46.310 us; speedup vs baseline: 3.2112x; 1.0763x over previous
//
#include <hip/hip_runtime.h>
#include <hip/hip_bf16.h>

#define NN 512
#define DD 128

typedef __bf16 bf16x8 __attribute__((ext_vector_type(8)));
typedef float f32x4 __attribute__((ext_vector_type(4)));

static __device__ __forceinline__ f32x4 mfma16(bf16x8 a, bf16x8 b, f32x4 c) {
  return __builtin_amdgcn_mfma_f32_16x16x32_bf16(a, b, c, 0, 0, 0);
}

// -------- phase 0 (fused): w1t transpose + hjp + cnt --------
__global__ void k_pre(const float* __restrict__ h,
                      const float* __restrict__ msg_w1,
                      const float* __restrict__ msg_b1,
                      const int* __restrict__ emask,
                      __bf16* __restrict__ w1t, float* __restrict__ hjp,
                      float* __restrict__ cnt) {
  __shared__ float hr[128];
  __shared__ int csum;
  int j = blockIdx.x, t = threadIdx.x;
  if (t == 0) csum = 0;
  hr[t] = h[j * 128 + t];
  __syncthreads();
  float acc = msg_b1[t];
  #pragma unroll 16
  for (int k = 0; k < 128; k++) acc += hr[k] * msg_w1[k * 128 + t];
  hjp[j * 128 + t] = acc;
  // w1t[e][k] = msg_w1[128+k][e] : 32 elements per block
  if (t < 32) {
    int tt = j * 32 + t;
    int e = tt >> 7, k = tt & 127;
    w1t[e * 128 + k] = (__bf16)msg_w1[(128 + k) * 128 + e];
  }
  // cnt[j] = sum_r emask[r][j]
  int s = 0;
  #pragma unroll
  for (int r = 0; r < 4; r++) s += emask[(t * 4 + r) * NN + j] ? 1 : 0;
  #pragma unroll
  for (int off = 32; off > 0; off >>= 1) s += __shfl_down(s, off, 64);
  if ((t & 63) == 0) atomicAdd(&csum, s);
  __syncthreads();
  if (t == 0) cnt[j] = (float)csum;
}

// ---------------- phase 1: T[i][e] = sum_j mask[j,i]*silu(pre[j,i,e]) ----
// R13 lesson: per-step compute (~200cy) << HBM latency (~900cy) and the
// depth-1 prefetch stalled every step at the publish vmcnt. This round:
// DEPTH-2 pipeline via unroll-2 with two static staging sets A/B --
//   even step jj: publish A (row jj+1), load row jj+3 -> A
//   odd  step   : publish B (row jj+2), load row jj+4 -> B
// so each load rests 2 full steps + 2 barriers before its ds_write.
// Publishes unconditional (regs prologue-zeroed; stale = finite; ms=0
// masks exactly -> bit-identical). emask hoisted to a 1KB LDS table mk[]
// (2 global loads/step -> ds_read 4B). Buffer parity: tile[r&1] holds
// row r; barrier at step s separates step s-2's reads from s's writes.
// (256,2) = cap 256, the only spill-free cap (R1-R10 allocator law).
#define CVT(bf, xa, xb) { \
  bf[0] = (__bf16)xa[0]; bf[1] = (__bf16)xa[1]; \
  bf[2] = (__bf16)xa[2]; bf[3] = (__bf16)xa[3]; \
  bf[4] = (__bf16)xb[0]; bf[5] = (__bf16)xb[1]; \
  bf[6] = (__bf16)xb[2]; bf[7] = (__bf16)xb[3]; }

__global__ __launch_bounds__(256, 2) void k_main(
    const float* __restrict__ rel, const int* __restrict__ emask,
    const float* __restrict__ hjp, const __bf16* __restrict__ w1t_g,
    float* __restrict__ partial) {
  __shared__ __align__(16) __bf16 tile[2 * 16 * 136];
  __shared__ float mk[256];
  const int tid = threadIdx.x;
  const int wave = tid >> 6;
  const int lane = tid & 63;
  const int l15 = lane & 15;
  const int q = lane >> 4;

  const int it = blockIdx.x >> 5;    // 0..31 : 16-row i-tile
  const int jc = blockIdx.x & 31;    // 0..31 : 16-col j-chunk
  const int irow = it * 16;
  const int jbase = jc * 16;

  // mask table: mk[jj*16 + row] = emask[jbase+jj][irow+row]
  mk[tid] = emask[(size_t)(jbase + (tid >> 4)) * NN + irow + (tid & 15)] ? 1.f : 0.f;

  // wave-private w1 fragments for e-slice [32w, 32w+32)
  bf16x8 aw00, aw01, aw02, aw03, aw10, aw11, aw12, aw13;
  {
    const __bf16* b0 = w1t_g + (wave * 32 + l15) * 128 + q * 8;
    aw00 = *(const bf16x8*)(b0);
    aw01 = *(const bf16x8*)(b0 + 32);
    aw02 = *(const bf16x8*)(b0 + 64);
    aw03 = *(const bf16x8*)(b0 + 96);
    const __bf16* b1 = b0 + 16 * 128;
    aw10 = *(const bf16x8*)(b1);
    aw11 = *(const bf16x8*)(b1 + 32);
    aw12 = *(const bf16x8*)(b1 + 64);
    aw13 = *(const bf16x8*)(b1 + 96);
  }

  // t0[r] = T[i=l15][e=32w+q*4+r], t1 = +16
  f32x4 t0 = {0.f, 0.f, 0.f, 0.f}, t1 = t0;

  // staging role: thread covers row srow, 8-float chunk schunk
  const int srow = tid >> 4;
  const int schunk = tid & 15;
  const float* sb = rel + ((size_t)jbase * NN + irow + srow) * DD + schunk * 8;
  __bf16* sd = tile + srow * 136 + schunk * 8;

  __syncthreads();   // mk visible

  // prologue: zero both staging sets; stage row0 -> tile[0]; row1 -> A;
  // row2 -> B. Stale contents are always finite; ms=0 masks exactly.
  f32x4 xa0 = {0.f, 0.f, 0.f, 0.f}, xb0 = xa0;   // set A
  f32x4 xa1 = xa0, xb1 = xa0;                     // set B
  {
    if (mk[srow] != 0.f) { xa0 = *(const f32x4*)sb; xb0 = *(const f32x4*)(sb + 4); }
    bf16x8 pub;
    CVT(pub, xa0, xb0)
    *(bf16x8*)sd = pub;
    xa0 = {0.f, 0.f, 0.f, 0.f}; xb0 = xa0;
    if (mk[16 + srow] != 0.f) {
      const float* s = sb + (size_t)NN * DD;
      xa0 = *(const f32x4*)s; xb0 = *(const f32x4*)(s + 4);
    }
    if (mk[32 + srow] != 0.f) {
      const float* s = sb + 2 * (size_t)NN * DD;
      xa1 = *(const f32x4*)s; xb1 = *(const f32x4*)(s + 4);
    }
  }

  #define COMPUTE(JROW, BUFOFF) { \
    const float ms = mk[(JROW) * 16 + l15]; \
    const __bf16* tp = tile + (BUFOFF) + l15 * 136 + q * 8; \
    bf16x8 bf0 = *(const bf16x8*)(tp); \
    bf16x8 bf1 = *(const bf16x8*)(tp + 32); \
    bf16x8 bf2 = *(const bf16x8*)(tp + 64); \
    bf16x8 bf3 = *(const bf16x8*)(tp + 96); \
    f32x4 p0 = {0.f, 0.f, 0.f, 0.f}, p1 = p0; \
    p0 = mfma16(aw00, bf0, p0); p1 = mfma16(aw10, bf0, p1); \
    p0 = mfma16(aw01, bf1, p0); p1 = mfma16(aw11, bf1, p1); \
    p0 = mfma16(aw02, bf2, p0); p1 = mfma16(aw12, bf2, p1); \
    p0 = mfma16(aw03, bf3, p0); p1 = mfma16(aw13, bf3, p1); \
    const float* hj = hjp + (size_t)(jbase + (JROW)) * DD + wave * 32 + q * 4; \
    f32x4 hv0 = *(const f32x4*)(hj); \
    f32x4 hv1 = *(const f32x4*)(hj + 16); \
    _Pragma("unroll") \
    for (int r = 0; r < 4; r++) { \
      float v0 = p0[r] + hv0[r]; \
      float v1 = p1[r] + hv1[r]; \
      t0[r] += ms * v0 * __builtin_amdgcn_rcpf(1.f + __expf(-v0)); \
      t1[r] += ms * v1 * __builtin_amdgcn_rcpf(1.f + __expf(-v1)); \
    } }

  #pragma unroll 1
  for (int jj = 0; jj < 16; jj += 2) {
    // ---- even step: compute row jj (tile[0]); publish A=row jj+1 -> tile[1]
    __syncthreads();
    {
      bf16x8 pub;
      CVT(pub, xa0, xb0)
      *(bf16x8*)(sd + 2176) = pub;
      if (jj + 3 < 16) {
        if (mk[(jj + 3) * 16 + srow] != 0.f) {
          const float* s = sb + (size_t)(jj + 3) * NN * DD;
          xa0 = *(const f32x4*)s; xb0 = *(const f32x4*)(s + 4);
        }
      }
    }
    COMPUTE(jj, 0)

    // ---- odd step: compute row jj+1 (tile[1]); publish B=row jj+2 -> tile[0]
    __syncthreads();
    {
      if (jj + 2 < 16) {
        bf16x8 pub;
        CVT(pub, xa1, xb1)
        *(bf16x8*)sd = pub;
      }
      if (jj + 4 < 16) {
        if (mk[(jj + 4) * 16 + srow] != 0.f) {
          const float* s = sb + (size_t)(jj + 4) * NN * DD;
          xa1 = *(const f32x4*)s; xb1 = *(const f32x4*)(s + 4);
        }
      }
    }
    COMPUTE(jj + 1, 2176)
  }
  #undef COMPUTE

  // direct per-wave e-slice write (no cross-wave reduction needed)
  float* pp = partial + ((size_t)jc * NN + irow + l15) * DD + wave * 32 + q * 4;
  *(f32x4*)pp = t0;
  *(f32x4*)(pp + 16) = t1;
}

// ------- phase 2: T-reduce + GEMM2(f32) + update MLP + LayerNorm -------
__global__ void k_update(const float* __restrict__ h, const float* __restrict__ partial,
                         const float* __restrict__ w2, const float* __restrict__ b2,
                         const float* __restrict__ cnt,
                         const float* __restrict__ uw1, const float* __restrict__ ub1,
                         const float* __restrict__ uw2, const float* __restrict__ ub2,
                         const float* __restrict__ g, const float* __restrict__ bb,
                         float* __restrict__ out) {
  __shared__ float Trow[128];
  __shared__ float uin[256];
  __shared__ float zl[128];
  __shared__ float ss[4];
  int i = blockIdx.x, t = threadIdx.x;
  float hv = h[i * 128 + t];
  float ts = 0.f;
  #pragma unroll
  for (int c = 0; c < 32; c++) ts += partial[((size_t)c * NN + i) * DD + t];
  Trow[t] = ts;
  __syncthreads();
  float a = cnt[i] * b2[t];
  #pragma unroll 16
  for (int e = 0; e < 128; e++) a += Trow[e] * w2[e * 128 + t];
  uin[t] = hv;
  uin[128 + t] = a;
  __syncthreads();
  float z = ub1[t];
  #pragma unroll 16
  for (int k = 0; k < 256; k++) z += uin[k] * uw1[k * 128 + t];
  z = z / (1.f + __expf(-z));
  zl[t] = z;
  __syncthreads();
  float dl = ub2[t];
  #pragma unroll 16
  for (int k = 0; k < 128; k++) dl += zl[k] * uw2[k * 128 + t];
  float x = hv + dl;
  float s1 = x, s2 = x * x;
  #pragma unroll
  for (int off = 32; off > 0; off >>= 1) {
    s1 += __shfl_down(s1, off, 64);
    s2 += __shfl_down(s2, off, 64);
  }
  if ((t & 63) == 0) { ss[(t >> 6) * 2] = s1; ss[(t >> 6) * 2 + 1] = s2; }
  __syncthreads();
  s1 = ss[0] + ss[2];
  s2 = ss[1] + ss[3];
  float mu = s1 * (1.f / 128.f);
  float var = s2 * (1.f / 128.f) - mu * mu;
  out[i * 128 + t] = (x - mu) * rsqrtf(var + 1e-5f) * g[t] + bb[t];
}

extern "C" void kernel_launch(void* const* d_in, const int* in_sizes, int n_in,
                              void* d_out, int out_size, void* d_ws, size_t ws_size,
                              hipStream_t stream) {
  const float* h      = (const float*)d_in[0];
  const float* rel    = (const float*)d_in[1];
  const int*   emask  = (const int*)d_in[2];
  const float* msg_w1 = (const float*)d_in[3];
  const float* msg_b1 = (const float*)d_in[4];
  const float* msg_w2 = (const float*)d_in[5];
  const float* msg_b2 = (const float*)d_in[6];
  const float* upd_w1 = (const float*)d_in[7];
  const float* upd_b1 = (const float*)d_in[8];
  const float* upd_w2 = (const float*)d_in[9];
  const float* upd_b2 = (const float*)d_in[10];
  const float* ln_g   = (const float*)d_in[11];
  const float* ln_b   = (const float*)d_in[12];
  float* out = (float*)d_out;

  char* ws = (char*)d_ws;
  float*  hjp     = (float*)ws;                        // 262144 B
  __bf16* w1t     = (__bf16*)(ws + 262144);            // 32768 B
  float*  cnt     = (float*)(ws + 262144 + 32768);     // 2048 B
  float*  partial = (float*)(ws + 262144 + 36864);     // 32*512*128*4 = 8 MiB

  k_pre<<<512, 128, 0, stream>>>(h, msg_w1, msg_b1, emask, w1t, hjp, cnt);
  k_main<<<1024, 256, 0, stream>>>(rel, emask, hjp, w1t, partial);
  k_update<<<512, 128, 0, stream>>>(h, partial, msg_w2, msg_b2, cnt,
                                    upd_w1, upd_b1, upd_w2, upd_b2,
                                    ln_g, ln_b, out);
}

// Round 15
// 43.173 us; speedup vs baseline: 3.4445x; 1.0727x over previous
//
#include <hip/hip_runtime.h>
#include <hip/hip_bf16.h>

#define NN 512
#define DD 128

typedef __bf16 bf16x8 __attribute__((ext_vector_type(8)));
typedef float f32x4 __attribute__((ext_vector_type(4)));

static __device__ __forceinline__ f32x4 mfma16(bf16x8 a, bf16x8 b, f32x4 c) {
  return __builtin_amdgcn_mfma_f32_16x16x32_bf16(a, b, c, 0, 0, 0);
}

// -------- phase 0 (fused): w1t transpose + hjp + cnt --------
__global__ void k_pre(const float* __restrict__ h,
                      const float* __restrict__ msg_w1,
                      const float* __restrict__ msg_b1,
                      const int* __restrict__ emask,
                      __bf16* __restrict__ w1t, float* __restrict__ hjp,
                      float* __restrict__ cnt) {
  __shared__ float hr[128];
  __shared__ int csum;
  int j = blockIdx.x, t = threadIdx.x;
  if (t == 0) csum = 0;
  hr[t] = h[j * 128 + t];
  __syncthreads();
  float a0 = msg_b1[t], a1 = 0.f;
  #pragma unroll 16
  for (int k = 0; k < 128; k += 2) {
    a0 += hr[k] * msg_w1[k * 128 + t];
    a1 += hr[k + 1] * msg_w1[(k + 1) * 128 + t];
  }
  hjp[j * 128 + t] = a0 + a1;
  // w1t[e][k] = msg_w1[128+k][e] : 32 elements per block
  if (t < 32) {
    int tt = j * 32 + t;
    int e = tt >> 7, k = tt & 127;
    w1t[e * 128 + k] = (__bf16)msg_w1[(128 + k) * 128 + e];
  }
  // cnt[j] = sum_r emask[r][j]
  int s = 0;
  #pragma unroll
  for (int r = 0; r < 4; r++) s += emask[(t * 4 + r) * NN + j] ? 1 : 0;
  #pragma unroll
  for (int off = 32; off > 0; off >>= 1) s += __shfl_down(s, off, 64);
  if ((t & 63) == 0) atomicAdd(&csum, s);
  __syncthreads();
  if (t == 0) cnt[j] = (float)csum;
}

// ---------------- phase 1: T[i][e] = sum_j mask[j,i]*silu(pre[j,i,e]) ----
// DEPTH-4 pipeline (R14 depth-2 rest ~600cy < 900cy HBM latency): four
// static staging sets A-D; step JR uses set JR&3: publish row JR+1 ->
// tile[(JR+1)&1], load row JR+5 -> same set. Rest = 4 steps (~1000cy).
// hjp block-slice (16 rows, 8KB) staged to LDS once: per-step hv reads
// become broadcast ds_reads (~60cy) instead of ~250cy L2 hits.
// Publishes unconditional-data (regs prologue-zeroed; stale = finite;
// ms=0 masks exactly -> bit-identical). mk[] = 1KB LDS mask table.
// (256,2) = cap 256, the only spill-free cap (R1-R10 allocator law).
#define CVT(bf, xa, xb) { \
  bf[0] = (__bf16)xa[0]; bf[1] = (__bf16)xa[1]; \
  bf[2] = (__bf16)xa[2]; bf[3] = (__bf16)xa[3]; \
  bf[4] = (__bf16)xb[0]; bf[5] = (__bf16)xb[1]; \
  bf[6] = (__bf16)xb[2]; bf[7] = (__bf16)xb[3]; }

__global__ __launch_bounds__(256, 2) void k_main(
    const float* __restrict__ rel, const int* __restrict__ emask,
    const float* __restrict__ hjp, const __bf16* __restrict__ w1t_g,
    float* __restrict__ partial) {
  __shared__ __align__(16) __bf16 tile[2 * 16 * 136];
  __shared__ float mk[256];
  __shared__ __align__(16) float hjl[16 * 128];
  const int tid = threadIdx.x;
  const int wave = tid >> 6;
  const int lane = tid & 63;
  const int l15 = lane & 15;
  const int q = lane >> 4;

  const int it = blockIdx.x >> 5;    // 0..31 : 16-row i-tile
  const int jc = blockIdx.x & 31;    // 0..31 : 16-col j-chunk
  const int irow = it * 16;
  const int jbase = jc * 16;

  // mask table + hjp slice staging
  mk[tid] = emask[(size_t)(jbase + (tid >> 4)) * NN + irow + (tid & 15)] ? 1.f : 0.f;
  {
    int r2 = tid >> 4, c8 = (tid & 15) * 8;
    const float* hsrc = hjp + (size_t)(jbase + r2) * DD + c8;
    *(f32x4*)(hjl + r2 * 128 + c8) = *(const f32x4*)hsrc;
    *(f32x4*)(hjl + r2 * 128 + c8 + 4) = *(const f32x4*)(hsrc + 4);
  }

  // wave-private w1 fragments for e-slice [32w, 32w+32)
  bf16x8 aw00, aw01, aw02, aw03, aw10, aw11, aw12, aw13;
  {
    const __bf16* b0 = w1t_g + (wave * 32 + l15) * 128 + q * 8;
    aw00 = *(const bf16x8*)(b0);
    aw01 = *(const bf16x8*)(b0 + 32);
    aw02 = *(const bf16x8*)(b0 + 64);
    aw03 = *(const bf16x8*)(b0 + 96);
    const __bf16* b1 = b0 + 16 * 128;
    aw10 = *(const bf16x8*)(b1);
    aw11 = *(const bf16x8*)(b1 + 32);
    aw12 = *(const bf16x8*)(b1 + 64);
    aw13 = *(const bf16x8*)(b1 + 96);
  }

  // t0[r] = T[i=l15][e=32w+q*4+r], t1 = +16
  f32x4 t0 = {0.f, 0.f, 0.f, 0.f}, t1 = t0;

  // staging role: thread covers row srow, 8-float chunk schunk
  const int srow = tid >> 4;
  const int schunk = tid & 15;
  const float* sb = rel + ((size_t)jbase * NN + irow + srow) * DD + schunk * 8;
  __bf16* sd = tile + srow * 136 + schunk * 8;

  __syncthreads();   // mk + hjl visible

  // prologue: zero all 4 staging sets; stage row0 -> tile[0];
  // load rows 1..4 -> A..D (predicated; stale contents finite; ms=0 masks).
  f32x4 xa0 = {0.f, 0.f, 0.f, 0.f}, xb0 = xa0;
  f32x4 xa1 = xa0, xb1 = xa0;
  f32x4 xa2 = xa0, xb2 = xa0;
  f32x4 xa3 = xa0, xb3 = xa0;
  {
    f32x4 ra = xa0, rb = xa0;
    if (mk[srow] != 0.f) { ra = *(const f32x4*)sb; rb = *(const f32x4*)(sb + 4); }
    bf16x8 pub;
    CVT(pub, ra, rb)
    *(bf16x8*)sd = pub;
    if (mk[16 + srow] != 0.f) {
      const float* s = sb + (size_t)NN * DD;
      xa0 = *(const f32x4*)s; xb0 = *(const f32x4*)(s + 4);
    }
    if (mk[32 + srow] != 0.f) {
      const float* s = sb + 2 * (size_t)NN * DD;
      xa1 = *(const f32x4*)s; xb1 = *(const f32x4*)(s + 4);
    }
    if (mk[48 + srow] != 0.f) {
      const float* s = sb + 3 * (size_t)NN * DD;
      xa2 = *(const f32x4*)s; xb2 = *(const f32x4*)(s + 4);
    }
    if (mk[64 + srow] != 0.f) {
      const float* s = sb + 4 * (size_t)NN * DD;
      xa3 = *(const f32x4*)s; xb3 = *(const f32x4*)(s + 4);
    }
  }

  #define COMPUTE(JROW) { \
    const float ms = mk[(JROW) * 16 + l15]; \
    const __bf16* tp = tile + (((JROW) & 1) ? 2176 : 0) + l15 * 136 + q * 8; \
    bf16x8 bf0 = *(const bf16x8*)(tp); \
    bf16x8 bf1 = *(const bf16x8*)(tp + 32); \
    bf16x8 bf2 = *(const bf16x8*)(tp + 64); \
    bf16x8 bf3 = *(const bf16x8*)(tp + 96); \
    f32x4 p0 = {0.f, 0.f, 0.f, 0.f}, p1 = p0; \
    p0 = mfma16(aw00, bf0, p0); p1 = mfma16(aw10, bf0, p1); \
    p0 = mfma16(aw01, bf1, p0); p1 = mfma16(aw11, bf1, p1); \
    p0 = mfma16(aw02, bf2, p0); p1 = mfma16(aw12, bf2, p1); \
    p0 = mfma16(aw03, bf3, p0); p1 = mfma16(aw13, bf3, p1); \
    const float* hj = hjl + (JROW) * 128 + wave * 32 + q * 4; \
    f32x4 hv0 = *(const f32x4*)(hj); \
    f32x4 hv1 = *(const f32x4*)(hj + 16); \
    _Pragma("unroll") \
    for (int r = 0; r < 4; r++) { \
      float v0 = p0[r] + hv0[r]; \
      float v1 = p1[r] + hv1[r]; \
      t0[r] += ms * v0 * __builtin_amdgcn_rcpf(1.f + __expf(-v0)); \
      t1[r] += ms * v1 * __builtin_amdgcn_rcpf(1.f + __expf(-v1)); \
    } }

  // STEP(JR, set): barrier; publish row JR+1 from set; load row JR+5 -> set;
  // compute row JR. Set rotation: step JR uses set JR&3 (reused at JR+4,
  // holding row JR+5 = (JR+4)+1). Rest = 4 steps per load.
  #define STEP(JR, XA, XB) { \
    __syncthreads(); \
    if ((JR) + 1 < 16) { \
      bf16x8 pub; \
      CVT(pub, XA, XB) \
      *(bf16x8*)(sd + ((((JR) + 1) & 1) ? 2176 : 0)) = pub; \
    } \
    if ((JR) + 5 < 16) { \
      if (mk[((JR) + 5) * 16 + srow] != 0.f) { \
        const float* s = sb + (size_t)((JR) + 5) * NN * DD; \
        XA = *(const f32x4*)s; XB = *(const f32x4*)(s + 4); \
      } \
    } \
    COMPUTE(JR) }

  #pragma unroll 1
  for (int jj = 0; jj < 16; jj += 4) {
    STEP(jj,     xa0, xb0)
    STEP(jj + 1, xa1, xb1)
    STEP(jj + 2, xa2, xb2)
    STEP(jj + 3, xa3, xb3)
  }
  #undef STEP
  #undef COMPUTE

  // direct per-wave e-slice write (no cross-wave reduction needed)
  float* pp = partial + ((size_t)jc * NN + irow + l15) * DD + wave * 32 + q * 4;
  *(f32x4*)pp = t0;
  *(f32x4*)(pp + 16) = t1;
}

// ------- phase 2: T-reduce + GEMM2(f32) + update MLP + LayerNorm -------
__global__ void k_update(const float* __restrict__ h, const float* __restrict__ partial,
                         const float* __restrict__ w2, const float* __restrict__ b2,
                         const float* __restrict__ cnt,
                         const float* __restrict__ uw1, const float* __restrict__ ub1,
                         const float* __restrict__ uw2, const float* __restrict__ ub2,
                         const float* __restrict__ g, const float* __restrict__ bb,
                         float* __restrict__ out) {
  __shared__ float Trow[128];
  __shared__ float uin[256];
  __shared__ float zl[128];
  __shared__ float ss[4];
  int i = blockIdx.x, t = threadIdx.x;
  float hv = h[i * 128 + t];
  float ts = 0.f;
  #pragma unroll
  for (int c = 0; c < 32; c++) ts += partial[((size_t)c * NN + i) * DD + t];
  Trow[t] = ts;
  __syncthreads();
  float a0 = cnt[i] * b2[t], a1 = 0.f;
  #pragma unroll 16
  for (int e = 0; e < 128; e += 2) {
    a0 += Trow[e] * w2[e * 128 + t];
    a1 += Trow[e + 1] * w2[(e + 1) * 128 + t];
  }
  uin[t] = hv;
  uin[128 + t] = a0 + a1;
  __syncthreads();
  float z0 = ub1[t], z1 = 0.f, z2 = 0.f, z3 = 0.f;
  #pragma unroll 16
  for (int k = 0; k < 256; k += 4) {
    z0 += uin[k] * uw1[k * 128 + t];
    z1 += uin[k + 1] * uw1[(k + 1) * 128 + t];
    z2 += uin[k + 2] * uw1[(k + 2) * 128 + t];
    z3 += uin[k + 3] * uw1[(k + 3) * 128 + t];
  }
  float z = (z0 + z1) + (z2 + z3);
  z = z / (1.f + __expf(-z));
  zl[t] = z;
  __syncthreads();
  float d0 = ub2[t], d1 = 0.f;
  #pragma unroll 16
  for (int k = 0; k < 128; k += 2) {
    d0 += zl[k] * uw2[k * 128 + t];
    d1 += zl[k + 1] * uw2[(k + 1) * 128 + t];
  }
  float x = hv + d0 + d1;
  float s1 = x, s2 = x * x;
  #pragma unroll
  for (int off = 32; off > 0; off >>= 1) {
    s1 += __shfl_down(s1, off, 64);
    s2 += __shfl_down(s2, off, 64);
  }
  if ((t & 63) == 0) { ss[(t >> 6) * 2] = s1; ss[(t >> 6) * 2 + 1] = s2; }
  __syncthreads();
  s1 = ss[0] + ss[2];
  s2 = ss[1] + ss[3];
  float mu = s1 * (1.f / 128.f);
  float var = s2 * (1.f / 128.f) - mu * mu;
  out[i * 128 + t] = (x - mu) * rsqrtf(var + 1e-5f) * g[t] + bb[t];
}

extern "C" void kernel_launch(void* const* d_in, const int* in_sizes, int n_in,
                              void* d_out, int out_size, void* d_ws, size_t ws_size,
                              hipStream_t stream) {
  const float* h      = (const float*)d_in[0];
  const float* rel    = (const float*)d_in[1];
  const int*   emask  = (const int*)d_in[2];
  const float* msg_w1 = (const float*)d_in[3];
  const float* msg_b1 = (const float*)d_in[4];
  const float* msg_w2 = (const float*)d_in[5];
  const float* msg_b2 = (const float*)d_in[6];
  const float* upd_w1 = (const float*)d_in[7];
  const float* upd_b1 = (const float*)d_in[8];
  const float* upd_w2 = (const float*)d_in[9];
  const float* upd_b2 = (const float*)d_in[10];
  const float* ln_g   = (const float*)d_in[11];
  const float* ln_b   = (const float*)d_in[12];
  float* out = (float*)d_out;

  char* ws = (char*)d_ws;
  float*  hjp     = (float*)ws;                        // 262144 B
  __bf16* w1t     = (__bf16*)(ws + 262144);            // 32768 B
  float*  cnt     = (float*)(ws + 262144 + 32768);     // 2048 B
  float*  partial = (float*)(ws + 262144 + 36864);     // 32*512*128*4 = 8 MiB

  k_pre<<<512, 128, 0, stream>>>(h, msg_w1, msg_b1, emask, w1t, hjp, cnt);
  k_main<<<1024, 256, 0, stream>>>(rel, emask, hjp, w1t, partial);
  k_update<<<512, 128, 0, stream>>>(h, partial, msg_w2, msg_b2, cnt,
                                    upd_w1, upd_b1, upd_w2, upd_b2,
                                    ln_g, ln_b, out);
}